// Round 10
// baseline (228.019 us; speedup 1.0000x reference)
//
#include <hip/hip_runtime.h>
#include <math.h>

// Problem constants
#define B_ 2
#define S_ 2048
#define D_ 1024
#define H_ 16
#define HKV_ 4
#define HD_ 64
#define SD_ 16

typedef __attribute__((ext_vector_type(8))) short bf16x8;
typedef __attribute__((ext_vector_type(4))) float f32x4;
typedef __attribute__((ext_vector_type(8))) unsigned short us8;
typedef __attribute__((ext_vector_type(4))) unsigned short us4;

#define LOG2E 1.4426950408889634f

__device__ __forceinline__ unsigned short f2bf(float f) {
  unsigned int u = __builtin_bit_cast(unsigned int, f);
  u += 0x7fffu + ((u >> 16) & 1u);   // RNE; inputs are finite
  return (unsigned short)(u >> 16);
}

// global -> LDS async DMA, 16B per lane; LDS dest wave-uniform base + lane*16.
__device__ __forceinline__ void gload16(const unsigned short* g, unsigned short* l) {
  __builtin_amdgcn_global_load_lds(
      (const __attribute__((address_space(1))) unsigned int*)g,
      (__attribute__((address_space(3))) unsigned int*)l, 16, 0, 0);
}

// ---------------------------------------------------------------------------
// Kernel 0: fp32 -> bf16 convert for GEMM operands.
// ---------------------------------------------------------------------------
__global__ __launch_bounds__(256) void convert_bf16(
    const float* __restrict__ x, const float* __restrict__ wq,
    const float* __restrict__ wk, const float* __restrict__ wv,
    const float* __restrict__ wo, unsigned short* __restrict__ xb,
    unsigned short* __restrict__ wqkv, unsigned short* __restrict__ wob) {
  const int blk = blockIdx.x;
  const float* src;
  unsigned short* dst;
  int off;
  if (blk < 2048)      { src = x;  dst = xb;             off = blk * 2048; }
  else if (blk < 2560) { src = wq; dst = wqkv;           off = (blk - 2048) * 2048; }
  else if (blk < 2688) { src = wk; dst = wqkv + 1048576; off = (blk - 2560) * 2048; }
  else if (blk < 2816) { src = wv; dst = wqkv + 1310720; off = (blk - 2688) * 2048; }
  else                 { src = wo; dst = wob;            off = (blk - 2816) * 2048; }
  const int i = off + threadIdx.x * 8;
  float4 a = *(const float4*)(src + i);
  float4 b = *(const float4*)(src + i + 4);
  us8 o;
  o[0] = f2bf(a.x); o[1] = f2bf(a.y); o[2] = f2bf(a.z); o[3] = f2bf(a.w);
  o[4] = f2bf(b.x); o[5] = f2bf(b.y); o[6] = f2bf(b.z); o[7] = f2bf(b.w);
  *(us8*)(dst + i) = o;
}

// ---------------------------------------------------------------------------
// Kernel A/D: bf16 MFMA GEMM, m97 staging, 64x128 tile.
// ---------------------------------------------------------------------------
__global__ __launch_bounds__(256) void gemm_bf16(
    const unsigned short* __restrict__ A, const unsigned short* __restrict__ Bm,
    const float* __restrict__ bias, float* __restrict__ C, int N) {
  __shared__ unsigned short As[64 * 64];
  __shared__ unsigned short Bs[128 * 64];
  const int tid = threadIdx.x;
  const int w = tid >> 6, lane = tid & 63;
  const int nm = lane & 15, quad = lane >> 4;
  const int m0 = blockIdx.y * 64, n0 = blockIdx.x * 128;
  const int wn = w * 32;

  f32x4 acc[4][2] = {};
  int arow[2], acol[2], brow[4], bcol[4];
#pragma unroll
  for (int it = 0; it < 2; ++it) {
    int s = it * 256 + tid;
    arow[it] = s >> 3;
    acol[it] = ((s & 7) ^ (arow[it] & 7)) * 8;
  }
#pragma unroll
  for (int it = 0; it < 4; ++it) {
    int s = it * 256 + tid;
    brow[it] = s >> 3;
    bcol[it] = ((s & 7) ^ (brow[it] & 7)) * 8;
  }

  for (int k0 = 0; k0 < 1024; k0 += 64) {
    __syncthreads();
#pragma unroll
    for (int it = 0; it < 2; ++it)
      gload16(A + (size_t)(m0 + arow[it]) * 1024 + k0 + acol[it],
              &As[(it * 256 + w * 64) * 8]);
#pragma unroll
    for (int it = 0; it < 4; ++it)
      gload16(Bm + (size_t)(n0 + brow[it]) * 1024 + k0 + bcol[it],
              &Bs[(it * 256 + w * 64) * 8]);
    __syncthreads();

#pragma unroll
    for (int ks = 0; ks < 2; ++ks) {
      const int cq = ks * 4 + quad;
      bf16x8 af[4], bfr[2];
#pragma unroll
      for (int mi = 0; mi < 4; ++mi) {
        const int m = mi * 16 + nm;
        af[mi] = *(const bf16x8*)&As[(m * 8 + (cq ^ (m & 7))) * 8];
      }
#pragma unroll
      for (int ni = 0; ni < 2; ++ni) {
        const int n = wn + ni * 16 + nm;
        bfr[ni] = *(const bf16x8*)&Bs[(n * 8 + (cq ^ (n & 7))) * 8];
      }
#pragma unroll
      for (int mi = 0; mi < 4; ++mi)
#pragma unroll
        for (int ni = 0; ni < 2; ++ni)
          acc[mi][ni] = __builtin_amdgcn_mfma_f32_16x16x32_bf16(
              af[mi], bfr[ni], acc[mi][ni], 0, 0, 0);
    }
  }

  float bv[2] = {0.f, 0.f};
  if (bias) {
#pragma unroll
    for (int ni = 0; ni < 2; ++ni) bv[ni] = bias[n0 + wn + ni * 16 + nm];
  }
#pragma unroll
  for (int mi = 0; mi < 4; ++mi) {
#pragma unroll
    for (int r = 0; r < 4; ++r) {
      const int row = m0 + mi * 16 + quad * 4 + r;
      float* crow = C + (size_t)row * N + n0 + wn + nm;
#pragma unroll
      for (int ni = 0; ni < 2; ++ni) crow[ni * 16] = acc[mi][ni][r] + bv[ni];
    }
  }
}

// ---------------------------------------------------------------------------
// Kernel B: RoPE + scatter (bf16) + low-rank sparsity proj (slots 0..19).
// q scaled by log2e/8, qsp by log2e/4 so attn uses native exp2.
// ---------------------------------------------------------------------------
__global__ __launch_bounds__(256) void rope_scatter(
    const float* __restrict__ P, const float* __restrict__ Ws,
    const float* __restrict__ bs, unsigned short* __restrict__ qh,
    unsigned short* __restrict__ kh, unsigned short* __restrict__ qsp,
    unsigned short* __restrict__ ksp) {
  __shared__ float wsl[16 * 64];
  __shared__ float bsl[16];
  __shared__ float rbuf[4][64];
  const int tid = threadIdx.x;
  const int row = blockIdx.x;
  const int b = row >> 11;
  const int s = row & 2047;
  {
    *(float4*)&wsl[tid * 4] = *(const float4*)&Ws[tid * 4];
    if (tid < 16) bsl[tid] = bs[tid];
  }
  __syncthreads();
  const int w = tid >> 6, lane = tid & 63;
  const int i = lane & 31, halfu = lane >> 5;
  const float theta = powf(10000.f, -((float)(2 * i) * (1.f / 64.f)));
  const float f = (float)s * theta;
  const float cf = cosf(f);
  const float sf = sinf(f);
  for (int slot = w; slot < 20; slot += 4) {
    float val = P[(size_t)row * 1536 + slot * 64 + lane];
    float partner = __shfl_xor(val, 32);
    float rot = halfu ? partner : -partner;
    float r = val * cf + rot * sf;
    unsigned short* dst;
    unsigned short* spdst;
    float qscale, spscale;
    if (slot < 16) {
      dst = qh + ((size_t)(b * 16 + slot) * 2048 + s) * 64;
      spdst = qsp + ((size_t)(b * 16 + slot) * 2048 + s) * 16;
      qscale = 0.125f * LOG2E; spscale = 0.25f * LOG2E;
    } else {
      int hh = slot - 16;
      dst = kh + ((size_t)(b * 4 + hh) * 2048 + s) * 64;
      spdst = ksp + ((size_t)(b * 4 + hh) * 2048 + s) * 16;
      qscale = 1.f; spscale = 1.f;
    }
    dst[lane] = f2bf(r * qscale);
    rbuf[w][lane] = r;
    int p = lane >> 4, j = lane & 15;
    float partial = 0.f;
#pragma unroll
    for (int t = 0; t < 16; ++t)
      partial += wsl[j * 64 + p * 16 + t] * rbuf[w][p * 16 + t];
    partial += __shfl_xor(partial, 16);
    partial += __shfl_xor(partial, 32);
    if (p == 0) spdst[j] = f2bf((partial + bsl[j]) * spscale);
  }
}

// ---------------------------------------------------------------------------
// Kernel B2: one-time V transpose: proj v-cols (f32) -> vt[bkv][d=64][s=2048] bf16.
// ---------------------------------------------------------------------------
__global__ __launch_bounds__(256) void v_transpose(
    const float* __restrict__ proj, unsigned short* __restrict__ vt) {
  __shared__ unsigned short t_[64 * 72];
  const int bkv = blockIdx.y;
  const int s0 = blockIdx.x * 64;
  const int b = bkv >> 2, hkv = bkv & 3;
  const int tid = threadIdx.x;
  const int sl = tid >> 2;
  const int c0 = (tid & 3) * 16;
  const float* src = proj + ((size_t)b * 2048 + s0 + sl) * 1536 + 1280 + hkv * 64 + c0;
  us8 o0, o1;
#pragma unroll
  for (int t = 0; t < 8; ++t) { o0[t] = f2bf(src[t]); o1[t] = f2bf(src[8 + t]); }
  *(us8*)&t_[sl * 72 + c0] = o0;
  *(us8*)&t_[sl * 72 + c0 + 8] = o1;
  __syncthreads();
  const int d = tid >> 2;
  const int sc_ = (tid & 3) * 16;
  us8 w0, w1;
#pragma unroll
  for (int t = 0; t < 8; ++t) w0[t] = t_[(sc_ + t) * 72 + d];
#pragma unroll
  for (int t = 0; t < 8; ++t) w1[t] = t_[(sc_ + 8 + t) * 72 + d];
  unsigned short* dst = vt + (size_t)bkv * 131072 + (size_t)d * 2048 + s0 + sc_;
  *(us8*)dst = w0;
  *(us8*)(dst + 8) = w1;
}

// ---------------------------------------------------------------------------
// Kernel C: gated causal flash attention. R10: paired q-tiles, q-split waves.
// Grid (16,32), 512 threads = 8 waves. Waves 0-3 own q-tile qxB=31-bx
// (rows qg*16..+15), waves 4-7 own qxA=bx. One shared key-tile loop
// jt=0..qxB; each wave computes the FULL 64-key tile for its 16 q-rows
// (R5's work-minimal wave shape: 16 scores/lane), skipping compute when
// jt > its qx (barriers still hit). Per-block issue work = 4(qxA+1)+4(qxB+1)
// = 132 tile-wave units for EVERY bx -> perfectly uniform, dispatch-order
// independent. 512 blocks = 2/CU -> up to 16 active waves/CU (2x R5).
// Per-wave register epilogue (no combine, no LDS scatter -> conflicts 0).
// ---------------------------------------------------------------------------
__global__ __launch_bounds__(512) void attn_kernel(
    const unsigned short* __restrict__ qh, const unsigned short* __restrict__ kh,
    const unsigned short* __restrict__ vt, const unsigned short* __restrict__ qsp,
    const unsigned short* __restrict__ ksp, unsigned short* __restrict__ ao) {
  __shared__ unsigned short Ks[64 * 64];
  __shared__ unsigned short Vs[64 * 64];
  __shared__ unsigned short Ksp[64 * 16];
  __shared__ unsigned short Pw[8][16 * 64];

  const int tid = threadIdx.x;
  const int w = tid >> 6;
  const int lane = tid & 63;
  const int nm = lane & 15;
  const int quad = lane >> 4;
  const int bx = blockIdx.x, bh = blockIdx.y;
  const int b = bh >> 4, h = bh & 15;
  const int hkv = h >> 2;
  const int qxA = bx, qxB = 31 - bx;
  const int myqx = (w >> 2) ? qxA : qxB;
  const int qg = w & 3;
  const int qrow0 = myqx * 64 + qg * 16;
  const size_t kbase = (size_t)(b * 4 + hkv) * 2048 * 64;
  const size_t vbase = (size_t)(b * 4 + hkv) * 131072;
  const size_t kspb = (size_t)(b * 4 + hkv) * 2048 * 16;

  // staging decode: 512 lanes cover the 512 16B chunks of Ks and of Vs
  const int r_ = tid >> 3;
  const int gc_ = (tid & 7) ^ (r_ & 7);
  unsigned short* pw = &Pw[w][0];

  const size_t qb = ((size_t)(b * 16 + h) * 2048 + qrow0 + nm) * 64;
  bf16x8 qa0 = *(const bf16x8*)(qh + qb + quad * 8);
  bf16x8 qa1 = *(const bf16x8*)(qh + qb + 32 + quad * 8);
  bf16x8 qspa = {0, 0, 0, 0, 0, 0, 0, 0};
  if (quad < 2)
    qspa = *(const bf16x8*)(qsp + ((size_t)(b * 16 + h) * 2048 + qrow0 + nm) * 16 + quad * 8);

  float l_r[4] = {0.f, 0.f, 0.f, 0.f};
  f32x4 O[4] = {{0.f, 0.f, 0.f, 0.f}, {0.f, 0.f, 0.f, 0.f},
                {0.f, 0.f, 0.f, 0.f}, {0.f, 0.f, 0.f, 0.f}};

  for (int jt = 0; jt <= qxB; ++jt) {
    const int j0 = jt * 64;
    __syncthreads();   // prior tile fully consumed by all waves
    gload16(kh + kbase + (size_t)(j0 + r_) * 64 + gc_ * 8, &Ks[w * 512]);
    gload16(vt + vbase + (size_t)r_ * 2048 + j0 + gc_ * 8, &Vs[w * 512]);
    if (w < 2)
      gload16(ksp + kspb + (size_t)(j0 + (tid >> 1)) * 16 + (tid & 1) * 8,
              &Ksp[w * 512]);
    __syncthreads();   // DMA drained + visible
    if (jt > myqx) continue;   // idle tail wave: barriers only

    // ---- QK^T + gate: 4 subtiles of 16 keys ----
#pragma unroll
    for (int st = 0; st < 4; ++st) {
      if (j0 + st * 16 > qrow0 + 15) {
        // fully-masked key group (diagonal tile): P must be zero
#pragma unroll
        for (int r = 0; r < 4; ++r) {
          const int prow = quad * 4 + r;
          const int chunk = (st * 2 + (nm >> 3)) ^ (prow & 7);
          pw[(prow * 8 + chunk) * 8 + (nm & 7)] = 0;
        }
        continue;
      }
      const int krow = st * 16 + nm;
      const int r7 = krow & 7;
      bf16x8 kb0 = *(const bf16x8*)&Ks[(krow * 8 + (quad ^ r7)) * 8];
      bf16x8 kb1 = *(const bf16x8*)&Ks[(krow * 8 + ((4 + quad) ^ r7)) * 8];
      bf16x8 gb = *(const bf16x8*)&Ksp[(krow * 2 + (quad & 1)) * 8];
      f32x4 z = {0.f, 0.f, 0.f, 0.f};
      f32x4 s = __builtin_amdgcn_mfma_f32_16x16x32_bf16(qa0, kb0, z, 0, 0, 0);
      s = __builtin_amdgcn_mfma_f32_16x16x32_bf16(qa1, kb1, s, 0, 0, 0);
      f32x4 g = __builtin_amdgcn_mfma_f32_16x16x32_bf16(qspa, gb, z, 0, 0, 0);
      const bool needmask = (j0 + st * 16 + 15 > qrow0);
#pragma unroll
      for (int r = 0; r < 4; ++r) {
        float gate = 1.f / (1.f + exp2f(-g[r]));   // g pre-scaled by log2e
        float v = s[r] * gate;                     // s pre-scaled by log2e
        if (needmask) {
          const int col = j0 + st * 16 + nm;
          const int rowg = qrow0 + quad * 4 + r;
          v = (col > rowg) ? -INFINITY : v;
        }
        float p = exp2f(v);        // exp2(-inf) == 0 handles the mask
        l_r[r] += p;
        const int prow = quad * 4 + r;
        const int chunk = (st * 2 + (nm >> 3)) ^ (prow & 7);
        pw[(prow * 8 + chunk) * 8 + (nm & 7)] = f2bf(p);
      }
    }

    // ---- PV: P (A-frag) x V^T rows (B-frag) ----
#pragma unroll
    for (int c = 0; c < 2; ++c) {
      const int gc = c * 4 + quad;
      bf16x8 pa = *(const bf16x8*)&pw[(nm * 8 + (gc ^ (nm & 7))) * 8];
#pragma unroll
      for (int dt = 0; dt < 4; ++dt) {
        const int vrow = dt * 16 + nm;
        bf16x8 vb = *(const bf16x8*)&Vs[(vrow * 8 + (gc ^ (vrow & 7))) * 8];
        O[dt] = __builtin_amdgcn_mfma_f32_16x16x32_bf16(pa, vb, O[dt], 0, 0, 0);
      }
    }
  }

  // ---- epilogue: reduce l across the 16 col-lanes once, scale, store ----
#pragma unroll
  for (int r = 0; r < 4; ++r) {
    float v = l_r[r];
    v += __shfl_xor(v, 1);
    v += __shfl_xor(v, 2);
    v += __shfl_xor(v, 4);
    v += __shfl_xor(v, 8);
    const float inv = 1.f / v;
    const int rowg = qrow0 + quad * 4 + r;
    unsigned short* orow = ao + ((size_t)b * 2048 + rowg) * 1024 + h * 64 + nm;
#pragma unroll
    for (int dt = 0; dt < 4; ++dt) orow[dt * 16] = f2bf(O[dt][r] * inv);
  }
}

// ---------------------------------------------------------------------------
extern "C" void kernel_launch(void* const* d_in, const int* in_sizes, int n_in,
                              void* d_out, int out_size, void* d_ws,
                              size_t ws_size, hipStream_t stream) {
  const float* x = (const float*)d_in[0];
  const float* Wq = (const float*)d_in[1];
  const float* Wk = (const float*)d_in[2];
  const float* Wv = (const float*)d_in[3];
  const float* Wo = (const float*)d_in[4];
  const float* bo = (const float*)d_in[5];
  const float* Ws = (const float*)d_in[6];
  const float* bs = (const float*)d_in[7];
  float* out = (float*)d_out;

  // Workspace layout (bytes):
  char* wsb = (char*)d_ws;
  float* proj = (float*)wsb;                                  // 25,165,824 B (dead after rope/vt)
  unsigned short* aob  = (unsigned short*)wsb;                // 8,388,608 B (alias proj head)
  unsigned short* qh   = (unsigned short*)(wsb + 25165824);   // 8,388,608 B
  unsigned short* kh   = (unsigned short*)(wsb + 33554432);   // 2,097,152 B
  unsigned short* vtb  = (unsigned short*)(wsb + 35651584);   // 2,097,152 B
  unsigned short* qsp  = (unsigned short*)(wsb + 37748736);   // 2,097,152 B
  unsigned short* ksp  = (unsigned short*)(wsb + 39845888);   //   524,288 B
  unsigned short* xb   = (unsigned short*)(wsb + 40370176);   // 8,388,608 B
  unsigned short* wqkv = (unsigned short*)(wsb + 48758784);   // 3,145,728 B
  unsigned short* wob  = (unsigned short*)(wsb + 51904512);   // 2,097,152 B

  convert_bf16<<<dim3(3328), 256, 0, stream>>>(x, Wq, Wk, Wv, Wo, xb, wqkv, wob);
  gemm_bf16<<<dim3(12, 64), 256, 0, stream>>>(xb, wqkv, nullptr, proj, 1536);
  rope_scatter<<<dim3(4096), 256, 0, stream>>>(proj, Ws, bs, qh, kh, qsp, ksp);
  v_transpose<<<dim3(32, 8), 256, 0, stream>>>(proj, vtb);
  attn_kernel<<<dim3(16, 32), 512, 0, stream>>>(qh, kh, vtb, qsp, ksp, aob);
  gemm_bf16<<<dim3(8, 64), 256, 0, stream>>>(aob, wob, bo, out, 1024);
}

// Round 11
// 205.199 us; speedup vs baseline: 1.1112x; 1.1112x over previous
//
#include <hip/hip_runtime.h>
#include <math.h>

// Problem constants
#define B_ 2
#define S_ 2048
#define D_ 1024
#define H_ 16
#define HKV_ 4
#define HD_ 64
#define SD_ 16

typedef __attribute__((ext_vector_type(8))) short bf16x8;
typedef __attribute__((ext_vector_type(4))) float f32x4;
typedef __attribute__((ext_vector_type(8))) unsigned short us8;
typedef __attribute__((ext_vector_type(4))) unsigned short us4;

#define LOG2E 1.4426950408889634f

__device__ __forceinline__ unsigned short f2bf(float f) {
  unsigned int u = __builtin_bit_cast(unsigned int, f);
  u += 0x7fffu + ((u >> 16) & 1u);   // RNE; inputs are finite
  return (unsigned short)(u >> 16);
}

// global -> LDS async DMA, 16B per lane; LDS dest wave-uniform base + lane*16.
__device__ __forceinline__ void gload16(const unsigned short* g, unsigned short* l) {
  __builtin_amdgcn_global_load_lds(
      (const __attribute__((address_space(1))) unsigned int*)g,
      (__attribute__((address_space(3))) unsigned int*)l, 16, 0, 0);
}

// ---------------------------------------------------------------------------
// Kernel 0: fp32 -> bf16 convert for GEMM operands.
// ---------------------------------------------------------------------------
__global__ __launch_bounds__(256) void convert_bf16(
    const float* __restrict__ x, const float* __restrict__ wq,
    const float* __restrict__ wk, const float* __restrict__ wv,
    const float* __restrict__ wo, unsigned short* __restrict__ xb,
    unsigned short* __restrict__ wqkv, unsigned short* __restrict__ wob) {
  const int blk = blockIdx.x;
  const float* src;
  unsigned short* dst;
  int off;
  if (blk < 2048)      { src = x;  dst = xb;             off = blk * 2048; }
  else if (blk < 2560) { src = wq; dst = wqkv;           off = (blk - 2048) * 2048; }
  else if (blk < 2688) { src = wk; dst = wqkv + 1048576; off = (blk - 2560) * 2048; }
  else if (blk < 2816) { src = wv; dst = wqkv + 1310720; off = (blk - 2688) * 2048; }
  else                 { src = wo; dst = wob;            off = (blk - 2816) * 2048; }
  const int i = off + threadIdx.x * 8;
  float4 a = *(const float4*)(src + i);
  float4 b = *(const float4*)(src + i + 4);
  us8 o;
  o[0] = f2bf(a.x); o[1] = f2bf(a.y); o[2] = f2bf(a.z); o[3] = f2bf(a.w);
  o[4] = f2bf(b.x); o[5] = f2bf(b.y); o[6] = f2bf(b.z); o[7] = f2bf(b.w);
  *(us8*)(dst + i) = o;
}

// ---------------------------------------------------------------------------
// Kernel A/D: bf16 MFMA GEMM, m97 staging, 64x128 tile.
// ---------------------------------------------------------------------------
__global__ __launch_bounds__(256) void gemm_bf16(
    const unsigned short* __restrict__ A, const unsigned short* __restrict__ Bm,
    const float* __restrict__ bias, float* __restrict__ C, int N) {
  __shared__ unsigned short As[64 * 64];
  __shared__ unsigned short Bs[128 * 64];
  const int tid = threadIdx.x;
  const int w = tid >> 6, lane = tid & 63;
  const int nm = lane & 15, quad = lane >> 4;
  const int m0 = blockIdx.y * 64, n0 = blockIdx.x * 128;
  const int wn = w * 32;

  f32x4 acc[4][2] = {};
  int arow[2], acol[2], brow[4], bcol[4];
#pragma unroll
  for (int it = 0; it < 2; ++it) {
    int s = it * 256 + tid;
    arow[it] = s >> 3;
    acol[it] = ((s & 7) ^ (arow[it] & 7)) * 8;
  }
#pragma unroll
  for (int it = 0; it < 4; ++it) {
    int s = it * 256 + tid;
    brow[it] = s >> 3;
    bcol[it] = ((s & 7) ^ (brow[it] & 7)) * 8;
  }

  for (int k0 = 0; k0 < 1024; k0 += 64) {
    __syncthreads();
#pragma unroll
    for (int it = 0; it < 2; ++it)
      gload16(A + (size_t)(m0 + arow[it]) * 1024 + k0 + acol[it],
              &As[(it * 256 + w * 64) * 8]);
#pragma unroll
    for (int it = 0; it < 4; ++it)
      gload16(Bm + (size_t)(n0 + brow[it]) * 1024 + k0 + bcol[it],
              &Bs[(it * 256 + w * 64) * 8]);
    __syncthreads();

#pragma unroll
    for (int ks = 0; ks < 2; ++ks) {
      const int cq = ks * 4 + quad;
      bf16x8 af[4], bfr[2];
#pragma unroll
      for (int mi = 0; mi < 4; ++mi) {
        const int m = mi * 16 + nm;
        af[mi] = *(const bf16x8*)&As[(m * 8 + (cq ^ (m & 7))) * 8];
      }
#pragma unroll
      for (int ni = 0; ni < 2; ++ni) {
        const int n = wn + ni * 16 + nm;
        bfr[ni] = *(const bf16x8*)&Bs[(n * 8 + (cq ^ (n & 7))) * 8];
      }
#pragma unroll
      for (int mi = 0; mi < 4; ++mi)
#pragma unroll
        for (int ni = 0; ni < 2; ++ni)
          acc[mi][ni] = __builtin_amdgcn_mfma_f32_16x16x32_bf16(
              af[mi], bfr[ni], acc[mi][ni], 0, 0, 0);
    }
  }

  float bv[2] = {0.f, 0.f};
  if (bias) {
#pragma unroll
    for (int ni = 0; ni < 2; ++ni) bv[ni] = bias[n0 + wn + ni * 16 + nm];
  }
#pragma unroll
  for (int mi = 0; mi < 4; ++mi) {
#pragma unroll
    for (int r = 0; r < 4; ++r) {
      const int row = m0 + mi * 16 + quad * 4 + r;
      float* crow = C + (size_t)row * N + n0 + wn + nm;
#pragma unroll
      for (int ni = 0; ni < 2; ++ni) crow[ni * 16] = acc[mi][ni][r] + bv[ni];
    }
  }
}

// ---------------------------------------------------------------------------
// Kernel B: RoPE + scatter (bf16) + low-rank sparsity proj (slots 0..19).
// q scaled by log2e/8, qsp by log2e/4 so attn uses native exp2.
// ---------------------------------------------------------------------------
__global__ __launch_bounds__(256) void rope_scatter(
    const float* __restrict__ P, const float* __restrict__ Ws,
    const float* __restrict__ bs, unsigned short* __restrict__ qh,
    unsigned short* __restrict__ kh, unsigned short* __restrict__ qsp,
    unsigned short* __restrict__ ksp) {
  __shared__ float wsl[16 * 64];
  __shared__ float bsl[16];
  __shared__ float rbuf[4][64];
  const int tid = threadIdx.x;
  const int row = blockIdx.x;
  const int b = row >> 11;
  const int s = row & 2047;
  {
    *(float4*)&wsl[tid * 4] = *(const float4*)&Ws[tid * 4];
    if (tid < 16) bsl[tid] = bs[tid];
  }
  __syncthreads();
  const int w = tid >> 6, lane = tid & 63;
  const int i = lane & 31, halfu = lane >> 5;
  const float theta = powf(10000.f, -((float)(2 * i) * (1.f / 64.f)));
  const float f = (float)s * theta;
  const float cf = cosf(f);
  const float sf = sinf(f);
  for (int slot = w; slot < 20; slot += 4) {
    float val = P[(size_t)row * 1536 + slot * 64 + lane];
    float partner = __shfl_xor(val, 32);
    float rot = halfu ? partner : -partner;
    float r = val * cf + rot * sf;
    unsigned short* dst;
    unsigned short* spdst;
    float qscale, spscale;
    if (slot < 16) {
      dst = qh + ((size_t)(b * 16 + slot) * 2048 + s) * 64;
      spdst = qsp + ((size_t)(b * 16 + slot) * 2048 + s) * 16;
      qscale = 0.125f * LOG2E; spscale = 0.25f * LOG2E;
    } else {
      int hh = slot - 16;
      dst = kh + ((size_t)(b * 4 + hh) * 2048 + s) * 64;
      spdst = ksp + ((size_t)(b * 4 + hh) * 2048 + s) * 16;
      qscale = 1.f; spscale = 1.f;
    }
    dst[lane] = f2bf(r * qscale);
    rbuf[w][lane] = r;
    int p = lane >> 4, j = lane & 15;
    float partial = 0.f;
#pragma unroll
    for (int t = 0; t < 16; ++t)
      partial += wsl[j * 64 + p * 16 + t] * rbuf[w][p * 16 + t];
    partial += __shfl_xor(partial, 16);
    partial += __shfl_xor(partial, 32);
    if (p == 0) spdst[j] = f2bf((partial + bsl[j]) * spscale);
  }
}

// ---------------------------------------------------------------------------
// Kernel B2: one-time V transpose: proj v-cols (f32) -> vt[bkv][d=64][s=2048] bf16.
// ---------------------------------------------------------------------------
__global__ __launch_bounds__(256) void v_transpose(
    const float* __restrict__ proj, unsigned short* __restrict__ vt) {
  __shared__ unsigned short t_[64 * 72];
  const int bkv = blockIdx.y;
  const int s0 = blockIdx.x * 64;
  const int b = bkv >> 2, hkv = bkv & 3;
  const int tid = threadIdx.x;
  const int sl = tid >> 2;
  const int c0 = (tid & 3) * 16;
  const float* src = proj + ((size_t)b * 2048 + s0 + sl) * 1536 + 1280 + hkv * 64 + c0;
  us8 o0, o1;
#pragma unroll
  for (int t = 0; t < 8; ++t) { o0[t] = f2bf(src[t]); o1[t] = f2bf(src[8 + t]); }
  *(us8*)&t_[sl * 72 + c0] = o0;
  *(us8*)&t_[sl * 72 + c0 + 8] = o1;
  __syncthreads();
  const int d = tid >> 2;
  const int sc_ = (tid & 3) * 16;
  us8 w0, w1;
#pragma unroll
  for (int t = 0; t < 8; ++t) w0[t] = t_[(sc_ + t) * 72 + d];
#pragma unroll
  for (int t = 0; t < 8; ++t) w1[t] = t_[(sc_ + 8 + t) * 72 + d];
  unsigned short* dst = vt + (size_t)bkv * 131072 + (size_t)d * 2048 + s0 + sc_;
  *(us8*)dst = w0;
  *(us8*)(dst + 8) = w1;
}

// ---------------------------------------------------------------------------
// Kernel C: gated causal flash attention. R11: revert to the R5 structure
// (fastest measured: 88 us) — grid (16,32), 256 thr, paired q-tiles
// {31-bx, bx} = uniform 33 tiles/block — and cut per-score VALU:
//  * __builtin_amdgcn_rcpf for the sigmoid (kills the ~9-inst IEEE divide
//    the compiler emits for 1.f/x without fast-math) and epilogue.
//  * __builtin_amdgcn_exp2f = bare v_exp_f32 (no libm wrapper).
//  * diagonal tiles: fully-masked 16-key groups skip MFMA+softmax, write 0.
// ---------------------------------------------------------------------------
__global__ __launch_bounds__(256) void attn_kernel(
    const unsigned short* __restrict__ qh, const unsigned short* __restrict__ kh,
    const unsigned short* __restrict__ vt, const unsigned short* __restrict__ qsp,
    const unsigned short* __restrict__ ksp, unsigned short* __restrict__ ao) {
  __shared__ unsigned short Ks[64 * 64];
  __shared__ unsigned short Vs[64 * 64];
  __shared__ unsigned short Ksp[64 * 16];
  __shared__ unsigned short Pw[4][16 * 64];

  const int tid = threadIdx.x;
  const int w = tid >> 6;
  const int lane = tid & 63;
  const int nm = lane & 15;
  const int quad = lane >> 4;
  const int bh = blockIdx.y;
  const int b = bh >> 4, h = bh & 15;
  const int hkv = h >> 2;
  const size_t kbase = (size_t)(b * 4 + hkv) * 2048 * 64;
  const size_t vbase = (size_t)(b * 4 + hkv) * 131072;
  const size_t kspb = (size_t)(b * 4 + hkv) * 2048 * 16;

  int srow_[2], scol_[2];
#pragma unroll
  for (int rd = 0; rd < 2; ++rd) {
    int Lc = rd * 256 + w * 64 + lane;
    int r = Lc >> 3;
    srow_[rd] = r;
    scol_[rd] = ((Lc & 7) ^ (r & 7)) * 8;
  }
  unsigned short* pw = &Pw[w][0];

  for (int ph = 0; ph < 2; ++ph) {
    const int qx = ph ? blockIdx.x : (31 - blockIdx.x);
    const int q0 = qx * 64;
    const int qrow0 = q0 + w * 16;

    const size_t qb = ((size_t)(b * 16 + h) * 2048 + qrow0 + nm) * 64;
    bf16x8 qa0 = *(const bf16x8*)(qh + qb + quad * 8);
    bf16x8 qa1 = *(const bf16x8*)(qh + qb + 32 + quad * 8);
    bf16x8 qspa = {0, 0, 0, 0, 0, 0, 0, 0};
    if (quad < 2)
      qspa = *(const bf16x8*)(qsp + ((size_t)(b * 16 + h) * 2048 + qrow0 + nm) * 16 + quad * 8);

    float l_r[4] = {0.f, 0.f, 0.f, 0.f};
    f32x4 O[4] = {{0.f, 0.f, 0.f, 0.f}, {0.f, 0.f, 0.f, 0.f},
                  {0.f, 0.f, 0.f, 0.f}, {0.f, 0.f, 0.f, 0.f}};

    const int ntile = qx + 1;
    for (int jt = 0; jt < ntile; ++jt) {
      const int j0 = jt * 64;
      __syncthreads();   // prior tile consumed by all waves
#pragma unroll
      for (int rd = 0; rd < 2; ++rd) {
        gload16(kh + kbase + (size_t)(j0 + srow_[rd]) * 64 + scol_[rd],
                &Ks[(rd * 256 + w * 64) * 8]);
        gload16(vt + vbase + (size_t)srow_[rd] * 2048 + j0 + scol_[rd],
                &Vs[(rd * 256 + w * 64) * 8]);
      }
      if (w < 2) {
        const int Lc = w * 64 + lane;
        gload16(ksp + kspb + (size_t)(j0 + (Lc >> 1)) * 16 + (Lc & 1) * 8,
                &Ksp[w * 512]);
      }
      __syncthreads();   // DMA drained + visible

      // ---- QK^T + gate -> p = exp2(s'*gate), accumulate l, write P ----
      const bool needmask = (j0 + 63 > qrow0);
#pragma unroll
      for (int st = 0; st < 4; ++st) {
        if (j0 + st * 16 > qrow0 + 15) {
          // fully-masked key group (diagonal tile): zero P, skip the math
#pragma unroll
          for (int r = 0; r < 4; ++r) {
            const int prow = quad * 4 + r;
            const int chunk = (st * 2 + (nm >> 3)) ^ (prow & 7);
            pw[(prow * 8 + chunk) * 8 + (nm & 7)] = 0;
          }
          continue;
        }
        const int krow = st * 16 + nm;
        const int r7 = krow & 7;
        bf16x8 kb0 = *(const bf16x8*)&Ks[(krow * 8 + (quad ^ r7)) * 8];
        bf16x8 kb1 = *(const bf16x8*)&Ks[(krow * 8 + ((4 + quad) ^ r7)) * 8];
        bf16x8 gb = *(const bf16x8*)&Ksp[(krow * 2 + (quad & 1)) * 8];
        f32x4 z = {0.f, 0.f, 0.f, 0.f};
        f32x4 s = __builtin_amdgcn_mfma_f32_16x16x32_bf16(qa0, kb0, z, 0, 0, 0);
        s = __builtin_amdgcn_mfma_f32_16x16x32_bf16(qa1, kb1, s, 0, 0, 0);
        f32x4 g = __builtin_amdgcn_mfma_f32_16x16x32_bf16(qspa, gb, z, 0, 0, 0);
        const bool edge = (j0 + st * 16 + 15 > qrow0);
#pragma unroll
        for (int r = 0; r < 4; ++r) {
          // sigmoid via raw v_rcp + v_exp (g pre-scaled by log2e)
          float gate = __builtin_amdgcn_rcpf(1.f + __builtin_amdgcn_exp2f(-g[r]));
          float v = s[r] * gate;                   // s pre-scaled by log2e
          if (edge) {
            const int col = j0 + st * 16 + nm;
            const int rowg = qrow0 + quad * 4 + r;
            v = (col > rowg) ? -INFINITY : v;
          }
          float p = __builtin_amdgcn_exp2f(v);     // exp2(-inf) == 0
          l_r[r] += p;
          const int prow = quad * 4 + r;
          const int chunk = (st * 2 + (nm >> 3)) ^ (prow & 7);
          pw[(prow * 8 + chunk) * 8 + (nm & 7)] = f2bf(p);
        }
      }

      // ---- PV: P (A-frag) x V^T rows (B-frag) ----
#pragma unroll
      for (int c = 0; c < 2; ++c) {
        const int gc = c * 4 + quad;
        bf16x8 pa = *(const bf16x8*)&pw[(nm * 8 + (gc ^ (nm & 7))) * 8];
#pragma unroll
        for (int dt = 0; dt < 4; ++dt) {
          const int vrow = dt * 16 + nm;
          bf16x8 vb = *(const bf16x8*)&Vs[(vrow * 8 + (gc ^ (vrow & 7))) * 8];
          O[dt] = __builtin_amdgcn_mfma_f32_16x16x32_bf16(pa, vb, O[dt], 0, 0, 0);
        }
      }
    }

    // ---- epilogue: reduce l across the 16 col-lanes once, scale, store ----
#pragma unroll
    for (int r = 0; r < 4; ++r) {
      float v = l_r[r];
      v += __shfl_xor(v, 1);
      v += __shfl_xor(v, 2);
      v += __shfl_xor(v, 4);
      v += __shfl_xor(v, 8);
      const float inv = __builtin_amdgcn_rcpf(v);
      const int rowg = qrow0 + quad * 4 + r;
      unsigned short* orow = ao + ((size_t)b * 2048 + rowg) * 1024 + h * 64 + nm;
#pragma unroll
      for (int dt = 0; dt < 4; ++dt) orow[dt * 16] = f2bf(O[dt][r] * inv);
    }
  }
}

// ---------------------------------------------------------------------------
extern "C" void kernel_launch(void* const* d_in, const int* in_sizes, int n_in,
                              void* d_out, int out_size, void* d_ws,
                              size_t ws_size, hipStream_t stream) {
  const float* x = (const float*)d_in[0];
  const float* Wq = (const float*)d_in[1];
  const float* Wk = (const float*)d_in[2];
  const float* Wv = (const float*)d_in[3];
  const float* Wo = (const float*)d_in[4];
  const float* bo = (const float*)d_in[5];
  const float* Ws = (const float*)d_in[6];
  const float* bs = (const float*)d_in[7];
  float* out = (float*)d_out;

  // Workspace layout (bytes):
  char* wsb = (char*)d_ws;
  float* proj = (float*)wsb;                                  // 25,165,824 B (dead after rope/vt)
  unsigned short* aob  = (unsigned short*)wsb;                // 8,388,608 B (alias proj head)
  unsigned short* qh   = (unsigned short*)(wsb + 25165824);   // 8,388,608 B
  unsigned short* kh   = (unsigned short*)(wsb + 33554432);   // 2,097,152 B
  unsigned short* vtb  = (unsigned short*)(wsb + 35651584);   // 2,097,152 B
  unsigned short* qsp  = (unsigned short*)(wsb + 37748736);   // 2,097,152 B
  unsigned short* ksp  = (unsigned short*)(wsb + 39845888);   //   524,288 B
  unsigned short* xb   = (unsigned short*)(wsb + 40370176);   // 8,388,608 B
  unsigned short* wqkv = (unsigned short*)(wsb + 48758784);   // 3,145,728 B
  unsigned short* wob  = (unsigned short*)(wsb + 51904512);   // 2,097,152 B

  convert_bf16<<<dim3(3328), 256, 0, stream>>>(x, Wq, Wk, Wv, Wo, xb, wqkv, wob);
  gemm_bf16<<<dim3(12, 64), 256, 0, stream>>>(xb, wqkv, nullptr, proj, 1536);
  rope_scatter<<<dim3(4096), 256, 0, stream>>>(proj, Ws, bs, qh, kh, qsp, ksp);
  v_transpose<<<dim3(32, 8), 256, 0, stream>>>(proj, vtb);
  attn_kernel<<<dim3(16, 32), 256, 0, stream>>>(qh, kh, vtb, qsp, ksp, aob);
  gemm_bf16<<<dim3(8, 64), 256, 0, stream>>>(aob, wob, bo, out, 1024);
}